// Round 3
// baseline (462.732 us; speedup 1.0000x reference)
//
#include <hip/hip_runtime.h>
#include <hip/hip_cooperative_groups.h>
#include <stdint.h>

namespace cg = cooperative_groups;

#define BS 256
#define MAXG 1024

// ---- helpers ----
__device__ __forceinline__ unsigned f2key(float f) {
    unsigned u = __float_as_uint(f);
    return (u & 0x80000000u) ? ~u : (u | 0x80000000u);
}
__device__ __forceinline__ float key2f(unsigned k) {
    unsigned u = (k & 0x80000000u) ? (k & 0x7FFFFFFFu) : ~k;
    return __uint_as_float(u);
}
// searchsorted(row_splits, i, 'right') - 1 over B+1 entries
__device__ __forceinline__ int find_seg(const int* rs, int B, int i) {
    int l = 0, h = B + 1;
    while (l < h) { int m = (l + h) >> 1; if (rs[m] <= i) l = m + 1; else h = m; }
    return l - 1;
}

// key(+inf) = 0xFF800000
#define KEY_INF 0xFF800000u

__launch_bounds__(BS, 4)
__global__ void k_coop(const float* __restrict__ x, const float* __restrict__ score,
                       const int* __restrict__ track, const int* __restrict__ rs,
                       int N, int B, int F, int nchunks, int cpb,
                       unsigned* __restrict__ seg_min, int* __restrict__ ws_total,
                       int* __restrict__ blk, int* __restrict__ part,
                       int* __restrict__ partbase,
                       float* __restrict__ out_x, float* __restrict__ out_rs,
                       float* __restrict__ out_old, float* __restrict__ out_idx,
                       float* __restrict__ out_nsel) {
    cg::grid_group grid = cg::this_grid();
    const int b = blockIdx.x;
    const int tid = threadIdx.x;
    const int G = gridDim.x;

    __shared__ unsigned smin[1024];
    __shared__ int wc[BS / 64];
    __shared__ int rows[BS];
    __shared__ int sh[BS];
    __shared__ float shT;

    // ---- P0: init seg_min ----
    if (b == 0) {
        for (int t = tid; t < B; t += BS) seg_min[t] = KEY_INF;
    }
    grid.sync();

    // ---- P1: segment min ----
    if (B <= 1024) {
        for (int t = tid; t < B; t += BS) smin[t] = KEY_INF;
        __syncthreads();
        for (long i = (long)b * BS + tid; i < N; i += (long)G * BS) {
            float s = track[i] ? 0.0f : score[i];
            int seg = find_seg(rs, B, (int)i);
            atomicMin(&smin[seg], f2key(s));
        }
        __syncthreads();
        for (int t = tid; t < B; t += BS)
            if (smin[t] != KEY_INF) atomicMin(&seg_min[t], smin[t]);
    } else {
        for (long i = (long)b * BS + tid; i < N; i += (long)G * BS) {
            float s = track[i] ? 0.0f : score[i];
            int seg = find_seg(rs, B, (int)i);
            atomicMin(&seg_min[seg], f2key(s));
        }
    }
    grid.sync();

    // ---- P2: threshold (per block) + per-chunk counts ----
    if (tid < 64) {
        float m = -INFINITY;
        for (int t = tid; t < B; t += 64) m = fmaxf(m, key2f(seg_min[t]));
        for (int d = 32; d > 0; d >>= 1) m = fmaxf(m, __shfl_xor(m, d));
        if (tid == 0) {
            const float invR = 1.0f / 10.0f;
            shT = (m < invR) ? invR : (m + 1e-7f);
        }
    }
    __syncthreads();
    const float T = shT;

    int bsum = 0;
    for (int j = 0; j < cpb; ++j) {
        int c = b * cpb + j;
        if (c >= nchunks) break;
        long i = (long)c * BS + tid;
        bool pred = (i < N) ? ((track[i] ? 0.0f : score[i]) <= T) : false;
        unsigned long long bal = __ballot(pred);
        int w = tid >> 6;
        if ((tid & 63) == 0) wc[w] = __popcll(bal);
        __syncthreads();
        int cnt = 0;
        for (int k = 0; k < BS / 64; ++k) cnt += wc[k];
        if (tid == 0) blk[c] = cnt;
        bsum += cnt;
        __syncthreads();
    }
    if (tid == 0) part[b] = bsum;
    grid.sync();

    // ---- P3: block 0 scans part[0..G) -> partbase (exclusive), total ----
    if (b == 0) {
        int ept = (G + BS - 1) / BS;
        int base = tid * ept;
        int mySum = 0;
        for (int j = 0; j < ept; ++j)
            if (base + j < G) mySum += part[base + j];
        sh[tid] = mySum;
        __syncthreads();
        for (int d = 1; d < BS; d <<= 1) {
            int add = (tid >= d) ? sh[tid - d] : 0;
            __syncthreads();
            sh[tid] += add;
            __syncthreads();
        }
        int run = sh[tid] - mySum;
        for (int j = 0; j < ept; ++j) {
            if (base + j < G) { int c = part[base + j]; partbase[base + j] = run; run += c; }
        }
        if (tid == BS - 1) {
            int tot = sh[BS - 1];
            *ws_total = tot;
            *out_nsel = (float)tot;
            *out_old = (float)N;
        }
    }
    grid.sync();

    const int total = *ws_total;
    const int Fv = F >> 2;
    const bool vec = ((F & 3) == 0) && (BS % (F >> 2) == 0);
    float4* out4 = (float4*)out_x;
    const float4* x4 = (const float4*)x;

    // ---- P4a: select + compacted row copy over owned chunks ----
    int running = partbase[b];
    for (int j = 0; j < cpb; ++j) {
        int c = b * cpb + j;
        if (c >= nchunks) break;
        long i = (long)c * BS + tid;
        bool pred = (i < N) ? ((track[i] ? 0.0f : score[i]) <= T) : false;
        unsigned long long bal = __ballot(pred);
        int lane = tid & 63;
        int w = tid >> 6;
        if (lane == 0) wc[w] = __popcll(bal);
        __syncthreads();
        int waveBase = 0;
        for (int k = 0; k < w; ++k) waveBase += wc[k];
        int cnt = 0;
        for (int k = 0; k < BS / 64; ++k) cnt += wc[k];
        if (pred) {
            int rank = waveBase + __popcll(bal & ((1ULL << (unsigned)lane) - 1ULL));
            rows[rank] = (int)i;
            out_idx[running + rank] = (float)i;
        }
        __syncthreads();
        if (vec) {
            int r0 = tid / Fv;
            int cc = tid - r0 * Fv;
            int rstep = BS / Fv;
            for (int r = r0; r < cnt; r += rstep)
                out4[(long)(running + r) * Fv + cc] = x4[(long)rows[r] * Fv + cc];
        } else {
            for (int e = tid; e < cnt * F; e += BS) {
                int r = e / F, cc = e - r * F;
                out_x[(long)(running + r) * F + cc] = x[(long)rows[r] * F + cc];
            }
        }
        running += cnt;
        __syncthreads();
    }

    // ---- P4b: new_rs (blocks 0..B, wave 0) ----
    if (b <= B && tid < 64) {
        int pos = rs[b];
        int ans;
        if (pos >= N) {
            ans = total;
        } else if (pos <= 0) {
            ans = 0;
        } else {
            int c = pos / BS;
            int owner = c / cpb;
            int off = partbase[owner];
            for (int c2 = owner * cpb; c2 < c; ++c2) off += blk[c2];
            int cnt = 0;
            for (int i = c * BS + tid; i < pos; i += 64)
                if ((track[i] ? 0.0f : score[i]) <= T) cnt++;
            for (int d = 32; d > 0; d >>= 1) cnt += __shfl_down(cnt, d);
            ans = off + cnt;
        }
        if (tid == 0) out_rs[b] = (float)ans;
    }

    // ---- P4c: zero tail rows of x_sel + (-1) tail of indices ----
    if (vec) {
        long zstart = (long)total * Fv;
        long zend = (long)N * Fv;
        for (long t = zstart + (long)b * BS + tid; t < zend; t += (long)G * BS)
            out4[t] = make_float4(0.0f, 0.0f, 0.0f, 0.0f);
    } else {
        long zstart = (long)total * F;
        long zend = (long)N * F;
        for (long t = zstart + (long)b * BS + tid; t < zend; t += (long)G * BS)
            out_x[t] = 0.0f;
    }
    for (long t = (long)total + (long)b * BS + tid; t < N; t += (long)G * BS)
        out_idx[t] = -1.0f;
}

extern "C" void kernel_launch(void* const* d_in, const int* in_sizes, int n_in,
                              void* d_out, int out_size, void* d_ws, size_t ws_size,
                              hipStream_t stream) {
    const float* x     = (const float*)d_in[0];
    const float* score = (const float*)d_in[1];
    const int*   track = (const int*)d_in[2];
    const int*   rs    = (const int*)d_in[3];

    int N = in_sizes[1];            // row count
    int F = in_sizes[0] / N;        // 32
    int B = in_sizes[3] - 1;        // 64
    int nchunks = (N + BS - 1) / BS;
    int G = nchunks < MAXG ? nchunks : MAXG;
    if (G < 1) G = 1;
    int cpb = (nchunks + G - 1) / G;

    // workspace layout (all 4-byte)
    unsigned* seg_min  = (unsigned*)d_ws;         // B
    int*      ws_total = (int*)(seg_min + B);     // 1
    int*      part     = ws_total + 1;            // G
    int*      partbase = part + MAXG;             // G
    int*      blk      = partbase + MAXG;         // nchunks

    // output layout (all stored as float32 values)
    float* out      = (float*)d_out;
    long off_rs   = (long)N * F;
    long off_old  = off_rs + (B + 1);
    long off_idx  = off_old + 1;
    long off_nsel = off_idx + N;

    float* out_x    = out;
    float* out_rs   = out + off_rs;
    float* out_old  = out + off_old;
    float* out_idx  = out + off_idx;
    float* out_nsel = out + off_nsel;

    void* args[] = {
        (void*)&x, (void*)&score, (void*)&track, (void*)&rs,
        (void*)&N, (void*)&B, (void*)&F, (void*)&nchunks, (void*)&cpb,
        (void*)&seg_min, (void*)&ws_total, (void*)&blk, (void*)&part, (void*)&partbase,
        (void*)&out_x, (void*)&out_rs, (void*)&out_old, (void*)&out_idx, (void*)&out_nsel
    };
    hipLaunchCooperativeKernel((void*)k_coop, dim3(G), dim3(BS), args, 0, stream);
}

// Round 4
// 142.317 us; speedup vs baseline: 3.2514x; 3.2514x over previous
//
#include <hip/hip_runtime.h>
#include <stdint.h>

#define BS 256
#define MAXCPB 32

typedef unsigned long long u64;

__device__ __forceinline__ unsigned ld_acq(unsigned* p) {
    return __hip_atomic_load(p, __ATOMIC_ACQUIRE, __HIP_MEMORY_SCOPE_AGENT);
}
__device__ __forceinline__ void st_rel(unsigned* p, unsigned v) {
    __hip_atomic_store(p, v, __ATOMIC_RELEASE, __HIP_MEMORY_SCOPE_AGENT);
}

// ---------------- Node 1: per-(segment,slot) partial min + zero lookback ----
// Grid = B*SPS blocks. Block b handles slot j of segment s (no atomics, no init).
__global__ __launch_bounds__(BS)
void k_segmin(const float* __restrict__ score, const int* __restrict__ track,
              const int* __restrict__ rs, int N, int B, int SPS,
              float* __restrict__ part_min, unsigned* __restrict__ look, int G2) {
    int b = blockIdx.x;
    int s = b / SPS, j = b - s * SPS;
    int r0 = rs[s], r1 = rs[s + 1];
    int len = r1 - r0;
    int per = (len + SPS - 1) / SPS;
    int a = r0 + j * per;
    int e = min(r1, a + per);
    float m = INFINITY;
    for (int i = a + (int)threadIdx.x; i < e; i += BS) {
        float v = track[i] ? 0.0f : score[i];
        m = fminf(m, v);
    }
    for (int d = 32; d > 0; d >>= 1) m = fminf(m, __shfl_down(m, d));
    __shared__ float wmin[BS / 64];
    if ((threadIdx.x & 63) == 0) wmin[threadIdx.x >> 6] = m;
    __syncthreads();
    if (threadIdx.x == 0) {
        float mm = wmin[0];
        for (int k = 1; k < BS / 64; ++k) mm = fminf(mm, wmin[k]);
        part_min[b] = mm;
    }
    // zero the lookback flags for node 2 (visible via kernel boundary)
    if (threadIdx.x == 0)
        for (int t = b; t < G2; t += gridDim.x) look[t] = 0u;
}

// ---------------- Node 2: threshold + ballots + lookback + compact + tails ----
__global__ __launch_bounds__(BS)
void k_main(const float* __restrict__ score, const int* __restrict__ track,
            const int* __restrict__ rsp, const float* __restrict__ x,
            int N, int B, int F, int SPS, int cpb,
            const float* __restrict__ part_min, unsigned* __restrict__ look,
            float* __restrict__ out_x, float* __restrict__ out_rs,
            float* __restrict__ out_old, float* __restrict__ out_idx,
            float* __restrict__ out_nsel) {
    const int b = blockIdx.x, tid = threadIdx.x;
    const int G2 = gridDim.x;
    const int RPB = cpb * BS;
    const int Rb = b * RPB;
    const int Lact = min(RPB, N - Rb);        // > 0 by grid construction
    const int w = tid >> 6, lane = tid & 63;

    __shared__ u64 smask[MAXCPB * (BS / 64)];
    __shared__ int rows[BS];
    __shared__ float shT;
    __shared__ int shBase, shTot, shCnt;

    // ---- threshold from part_min: max over segments of (min over SPS slots) ----
    if (tid < 64) {
        float m = -INFINITY;
        for (int s = tid; s < B; s += 64) {
            float mn = INFINITY;
            for (int j = 0; j < SPS; ++j) mn = fminf(mn, part_min[s * SPS + j]);
            m = fmaxf(m, mn);
        }
        for (int d = 32; d > 0; d >>= 1) m = fmaxf(m, __shfl_xor(m, d));
        if (tid == 0) {
            const float invR = 0.1f;
            shT = (m < invR) ? invR : (m + 1e-7f);
        }
    }
    __syncthreads();
    const float T = shT;

    // ---- phase A: per-chunk ballots into LDS ----
    for (int c = 0; c < cpb; ++c) {
        int i = Rb + c * BS + tid;
        bool pred = false;
        if (i < N) pred = ((track[i] ? 0.0f : score[i]) <= T);
        u64 bal = __ballot(pred);
        if (lane == 0) smask[c * 4 + w] = bal;
    }
    __syncthreads();

    // ---- block count ----
    if (tid < 64) {
        int nwords = cpb * 4;
        int c = 0;
        for (int t = tid; t < nwords; t += 64) c += __popcll(smask[t]);
        for (int d = 32; d > 0; d >>= 1) c += __shfl_down(c, d);
        if (tid == 0) shCnt = c;
    }
    __syncthreads();
    const int myCnt = shCnt;

    // ---- decoupled lookback (wave 0, 64-wide windows) ----
    if (tid < 64) {
        if (tid == 0) st_rel(&look[b], (1u << 29) | (unsigned)myCnt);
        unsigned excl = 0;
        int p = b - 1;
        while (p >= 0) {
            int idx = p - tid;
            bool act = idx >= 0;
            unsigned v = 0;
            if (act) { do { v = ld_acq(&look[idx]); } while (v == 0u); }
            unsigned fl = v >> 29;
            unsigned cnt = v & 0x1FFFFFFFu;
            u64 pm = __ballot(act && fl == 2u);
            if (pm) {
                int L = __ffsll((long long)pm) - 1;   // nearest PREFIX lane
                unsigned contrib = (tid <= L) ? cnt : 0;  // aggs < L, inclusive at L
                for (int d = 32; d > 0; d >>= 1) contrib += __shfl_down(contrib, d);
                excl += __shfl(contrib, 0);
                break;
            } else {
                unsigned contrib = act ? cnt : 0;
                for (int d = 32; d > 0; d >>= 1) contrib += __shfl_down(contrib, d);
                excl += __shfl(contrib, 0);
                p -= 64;
            }
        }
        if (tid == 0) {
            unsigned inc = excl + (unsigned)myCnt;
            shBase = (int)excl;
            shTot = (int)inc;
            st_rel(&look[b], (2u << 29) | inc);
            if (b == G2 - 1) { out_nsel[0] = (float)inc; out_old[0] = (float)N; }
        }
    }
    __syncthreads();
    const int myBase = shBase;

    const int Fv = F >> 2;
    const bool vec = ((F & 3) == 0) && (Fv > 0) && (BS % Fv == 0);
    const float4* x4 = (const float4*)x;
    float4* out4 = (float4*)out_x;

    // ---- phase B: compacted row copy + idx writes ----
    int running = 0;
    for (int c = 0; c < cpb; ++c) {
        u64 w0 = smask[c * 4 + 0], w1 = smask[c * 4 + 1];
        u64 w2 = smask[c * 4 + 2], w3 = smask[c * 4 + 3];
        int p0 = __popcll(w0), p1 = __popcll(w1), p2 = __popcll(w2), p3 = __popcll(w3);
        int ccnt = p0 + p1 + p2 + p3;
        if (ccnt == 0) continue;                 // block-uniform
        u64 mybal = (w == 0) ? w0 : (w == 1) ? w1 : (w == 2) ? w2 : w3;
        int wb = (w > 0 ? p0 : 0) + (w > 1 ? p1 : 0) + (w > 2 ? p2 : 0);
        bool pred = (mybal >> (unsigned)lane) & 1ULL;
        if (pred) {
            int rank = wb + __popcll(mybal & ((1ULL << (unsigned)lane) - 1ULL));
            int row = Rb + c * BS + tid;
            rows[rank] = row;
            out_idx[(long)myBase + running + rank] = (float)row;
        }
        __syncthreads();
        long dstbase = (long)myBase + running;
        if (vec) {
            int r0 = tid / Fv, cc = tid - (tid / Fv) * Fv, rstep = BS / Fv;
            for (int r = r0; r < ccnt; r += rstep)
                out4[(dstbase + r) * Fv + cc] = x4[(long)rows[r] * Fv + cc];
        } else {
            for (int e = tid; e < ccnt * F; e += BS) {
                int r = e / F, cc = e - r * F;
                out_x[(dstbase + r) * F + cc] = x[(long)rows[r] * F + cc];
            }
        }
        running += ccnt;
        __syncthreads();
    }

    // ---- reverse-tiled tail: zeros for x rows, -1 for idx (no global total!) ----
    int unsel = Lact - myCnt;
    long Unext = (long)(Rb + Lact) - (long)(myBase + myCnt);  // unselected prefix U_{b+1}
    long zr0 = (long)N - Unext;
    if (vec) {
        long e0 = zr0 * Fv;
        long ecnt = (long)unsel * Fv;
        float4 z = make_float4(0.0f, 0.0f, 0.0f, 0.0f);
        for (long e = tid; e < ecnt; e += BS) out4[e0 + e] = z;
    } else {
        long e0 = zr0 * (long)F;
        long ecnt = (long)unsel * F;
        for (long e = tid; e < ecnt; e += BS) out_x[e0 + e] = 0.0f;
    }
    for (int t = tid; t < unsel; t += BS) out_idx[zr0 + t] = -1.0f;

    // ---- new_rs: boundaries owned by this block (pos==N -> last block) ----
    const int tot = shTot;
    for (int s = tid; s <= B; s += BS) {
        int pos = rsp[s];
        if (pos >= Rb && pos < Rb + Lact) {
            int rel = pos - Rb;
            int nw = rel >> 6, rem = rel & 63;
            int cnt = 0;
            for (int ww = 0; ww < nw; ++ww) cnt += __popcll(smask[ww]);
            if (rem) cnt += __popcll(smask[nw] & ((1ULL << (unsigned)rem) - 1ULL));
            out_rs[s] = (float)(myBase + cnt);
        } else if (b == G2 - 1 && pos >= N) {
            out_rs[s] = (float)tot;
        }
    }
}

extern "C" void kernel_launch(void* const* d_in, const int* in_sizes, int n_in,
                              void* d_out, int out_size, void* d_ws, size_t ws_size,
                              hipStream_t stream) {
    const float* x     = (const float*)d_in[0];
    const float* score = (const float*)d_in[1];
    const int*   track = (const int*)d_in[2];
    const int*   rs    = (const int*)d_in[3];

    int N = in_sizes[1];            // rows
    int F = in_sizes[0] / N;        // 32
    int B = in_sizes[3] - 1;        // 64

    int nchunks = (N + BS - 1) / BS;
    int cpb = (nchunks + 1023) / 1024;
    if (cpb < 1) cpb = 1;
    if (cpb > MAXCPB) cpb = MAXCPB;
    int G2 = (nchunks + cpb - 1) / cpb;   // every block non-empty

    int SPS = B > 0 ? (1024 / B) : 1;
    if (SPS < 1) SPS = 1;
    if (SPS > 64) SPS = 64;
    int G1 = B * SPS;

    // workspace
    float*    part_min = (float*)d_ws;                       // G1 floats
    unsigned* look     = (unsigned*)((char*)d_ws + (1 << 20)); // G2 words

    // output layout (all float32 values)
    float* out      = (float*)d_out;
    long off_rs   = (long)N * F;
    long off_old  = off_rs + (B + 1);
    long off_idx  = off_old + 1;
    long off_nsel = off_idx + N;

    float* out_x    = out;
    float* out_rs   = out + off_rs;
    float* out_old  = out + off_old;
    float* out_idx  = out + off_idx;
    float* out_nsel = out + off_nsel;

    k_segmin<<<G1, BS, 0, stream>>>(score, track, rs, N, B, SPS, part_min, look, G2);
    k_main<<<G2, BS, 0, stream>>>(score, track, rs, x, N, B, F, SPS, cpb,
                                  part_min, look, out_x, out_rs, out_old, out_idx, out_nsel);
}

// Round 5
// 83.523 us; speedup vs baseline: 5.5402x; 1.7039x over previous
//
#include <hip/hip_runtime.h>
#include <stdint.h>

#define BS 256
#define CPB 4          // chunks (of BS rows) per block in count/main

typedef unsigned long long u64;

// ---------------- Node 1: per-(segment,slot) partial min ----------------
__global__ __launch_bounds__(BS)
void k_segmin(const float* __restrict__ score, const int* __restrict__ track,
              const int* __restrict__ rs, int B, int SPS,
              float* __restrict__ part_min) {
    int b = blockIdx.x;
    int s = b / SPS, j = b - s * SPS;
    int r0 = rs[s], r1 = rs[s + 1];
    int len = r1 - r0;
    int per = (len + SPS - 1) / SPS;
    int a = r0 + j * per;
    int e = min(r1, a + per);
    float m = INFINITY;
    for (int i = a + (int)threadIdx.x; i < e; i += BS)
        m = fminf(m, track[i] ? 0.0f : score[i]);
    for (int d = 32; d > 0; d >>= 1) m = fminf(m, __shfl_down(m, d));
    __shared__ float wmin[BS / 64];
    if ((threadIdx.x & 63) == 0) wmin[threadIdx.x >> 6] = m;
    __syncthreads();
    if (threadIdx.x == 0) {
        float mm = wmin[0];
        for (int k = 1; k < BS / 64; ++k) mm = fminf(mm, wmin[k]);
        part_min[b] = mm;
    }
}

// ---------------- Node 2: threshold + ballots -> masks + counts ----------
__global__ __launch_bounds__(BS)
void k_count(const float* __restrict__ score, const int* __restrict__ track,
             const float* __restrict__ part_min, int N, int B, int SPS,
             u64* __restrict__ gmask, int* __restrict__ cnts) {
    const int b = blockIdx.x, tid = threadIdx.x;
    const int w = tid >> 6, lane = tid & 63;
    __shared__ float shT;
    __shared__ u64 smask[CPB * 4];

    if (tid < 64) {
        float m = -INFINITY;
        for (int s = tid; s < B; s += 64) {
            float mn = INFINITY;
            for (int j = 0; j < SPS; ++j) mn = fminf(mn, part_min[s * SPS + j]);
            m = fmaxf(m, mn);
        }
        for (int d = 32; d > 0; d >>= 1) m = fmaxf(m, __shfl_xor(m, d));
        if (tid == 0) shT = (m < 0.1f) ? 0.1f : (m + 1e-7f);
    }
    __syncthreads();
    const float T = shT;

    const long Rb = (long)b * CPB * BS;
    for (int c = 0; c < CPB; ++c) {
        long i = Rb + (long)c * BS + tid;
        bool pred = (i < N) && ((track[i] ? 0.0f : score[i]) <= T);
        u64 bal = __ballot(pred);
        if (lane == 0) smask[c * 4 + w] = bal;
    }
    __syncthreads();
    if (tid < CPB * 4) gmask[(long)b * CPB * 4 + tid] = smask[tid];
    if (tid == 0) {
        int c = 0;
        for (int k = 0; k < CPB * 4; ++k) c += __popcll(smask[k]);
        cnts[b] = c;
    }
}

// ---------------- Node 3: prefix + compact copy + tails + new_rs ---------
__global__ __launch_bounds__(BS)
void k_main(const float* __restrict__ x, const int* __restrict__ rsp,
            const u64* __restrict__ gmask, const int* __restrict__ cnts,
            int N, int B, int F, int G2,
            float* __restrict__ out_x, float* __restrict__ out_rs,
            float* __restrict__ out_old, float* __restrict__ out_idx,
            float* __restrict__ out_nsel) {
    const int b = blockIdx.x, tid = threadIdx.x;
    const int w = tid >> 6, lane = tid & 63;
    const int RPB = CPB * BS;
    const int Rb = b * RPB;
    const int Lact = min(RPB, N - Rb);

    __shared__ u64 smask[CPB * 4];
    __shared__ int chunkcnt[CPB];
    __shared__ int rows[CPB * BS];
    __shared__ int shBase, shTot;

    if (tid < CPB * 4) smask[tid] = gmask[(long)b * CPB * 4 + tid];

    // exclusive prefix of cnts up to b, plus grand total (no sync, no atomics)
    if (tid < 64) {
        int pre = 0, tot = 0;
        for (int k = tid; k < G2; k += 64) {
            int c = cnts[k];
            tot += c;
            pre += (k < b) ? c : 0;
        }
        for (int d = 32; d > 0; d >>= 1) {
            pre += __shfl_down(pre, d);
            tot += __shfl_down(tot, d);
        }
        if (tid == 0) { shBase = pre; shTot = tot; }
    }
    __syncthreads();
    if (tid < CPB) {
        const u64* mw = &smask[tid * 4];
        chunkcnt[tid] = __popcll(mw[0]) + __popcll(mw[1]) + __popcll(mw[2]) + __popcll(mw[3]);
    }
    __syncthreads();
    const int myBase = shBase, total = shTot;

    if (b == 0 && tid == 0) { out_nsel[0] = (float)total; out_old[0] = (float)N; }

    // build compacted row list in LDS + write indices output
    int bcnt = 0;
    {
        int basec = 0;
        for (int c = 0; c < CPB; ++c) {
            u64 mybal = smask[c * 4 + w];
            int wb = 0;
            for (int k = 0; k < w; ++k) wb += __popcll(smask[c * 4 + k]);
            if ((mybal >> (unsigned)lane) & 1ULL) {
                int rank = basec + wb + __popcll(mybal & ((1ULL << (unsigned)lane) - 1ULL));
                int row = Rb + c * BS + tid;
                rows[rank] = row;
                out_idx[(long)myBase + rank] = (float)row;
            }
            basec += chunkcnt[c];
        }
        bcnt = basec;
    }
    __syncthreads();

    const int Fv = F >> 2;
    const bool vec = ((F & 3) == 0) && (Fv > 0) && (BS % Fv == 0);
    const float4* x4 = (const float4*)x;
    float4* out4 = (float4*)out_x;

    // flat barrier-free gather/copy of selected rows
    if (vec) {
        int r0 = tid / Fv, cc = tid - r0 * Fv, rstep = BS / Fv;
        for (int r = r0; r < bcnt; r += rstep)
            out4[((long)myBase + r) * Fv + cc] = x4[(long)rows[r] * Fv + cc];
    } else {
        for (int e = tid; e < bcnt * F; e += BS) {
            int r = e / F, cc = e - r * F;
            out_x[((long)myBase + r) * F + cc] = x[(long)rows[r] * F + cc];
        }
    }

    // reverse-tiled tails: zeros for x rows, -1 for idx
    int unsel = Lact - bcnt;
    long Unext = (long)(Rb + Lact) - (long)(myBase + bcnt);
    long zr0 = (long)N - Unext;
    if (vec) {
        float4 z = make_float4(0.0f, 0.0f, 0.0f, 0.0f);
        long e0 = zr0 * Fv, ecnt = (long)unsel * Fv;
        for (long e = tid; e < ecnt; e += BS) out4[e0 + e] = z;
    } else {
        long e0 = zr0 * (long)F, ecnt = (long)unsel * F;
        for (long e = tid; e < ecnt; e += BS) out_x[e0 + e] = 0.0f;
    }
    for (int t = tid; t < unsel; t += BS) out_idx[zr0 + t] = -1.0f;

    // new_rs boundaries owned by this block (pos>=N -> last block)
    for (int s = tid; s <= B; s += BS) {
        int pos = rsp[s];
        if (pos >= Rb && pos < Rb + Lact) {
            int rel = pos - Rb;
            int nw = rel >> 6, rem = rel & 63;
            int cnt = 0;
            for (int k = 0; k < nw; ++k) cnt += __popcll(smask[k]);
            if (rem) cnt += __popcll(smask[nw] & ((1ULL << (unsigned)rem) - 1ULL));
            out_rs[s] = (float)(myBase + cnt);
        } else if (b == G2 - 1 && pos >= N) {
            out_rs[s] = (float)total;
        }
    }
}

extern "C" void kernel_launch(void* const* d_in, const int* in_sizes, int n_in,
                              void* d_out, int out_size, void* d_ws, size_t ws_size,
                              hipStream_t stream) {
    const float* x     = (const float*)d_in[0];
    const float* score = (const float*)d_in[1];
    const int*   track = (const int*)d_in[2];
    const int*   rs    = (const int*)d_in[3];

    int N = in_sizes[1];            // rows
    int F = in_sizes[0] / N;        // 32
    int B = in_sizes[3] - 1;        // 64

    int nchunks = (N + BS - 1) / BS;
    int G2 = (nchunks + CPB - 1) / CPB;

    int SPS = B > 0 ? (1024 / B) : 1;
    if (SPS < 1) SPS = 1;
    if (SPS > 64) SPS = 64;
    int G1 = B * SPS;

    // workspace layout
    float* part_min = (float*)d_ws;                 // G1 floats
    int*   cnts     = (int*)(part_min + G1);        // G2 ints
    u64*   gmask    = (u64*)(((uintptr_t)(cnts + G2) + 15) & ~(uintptr_t)15); // G2*CPB*4

    // output layout (all float32 values)
    float* out      = (float*)d_out;
    long off_rs   = (long)N * F;
    long off_old  = off_rs + (B + 1);
    long off_idx  = off_old + 1;
    long off_nsel = off_idx + N;

    float* out_x    = out;
    float* out_rs   = out + off_rs;
    float* out_old  = out + off_old;
    float* out_idx  = out + off_idx;
    float* out_nsel = out + off_nsel;

    k_segmin<<<G1, BS, 0, stream>>>(score, track, rs, B, SPS, part_min);
    k_count<<<G2, BS, 0, stream>>>(score, track, part_min, N, B, SPS, gmask, cnts);
    k_main<<<G2, BS, 0, stream>>>(x, rs, gmask, cnts, N, B, F, G2,
                                  out_x, out_rs, out_old, out_idx, out_nsel);
}